// Round 11
// baseline (24.870 us; speedup 1.0000x reference)
//
#include <hip/hip_runtime.h>
#include <math.h>

// GaussianVisibility: R rays x B=24 bones x G=4 gaussians -> shadow map (R,)
// w2ls (R,24,4,4) fp32 = 100.7 MB stream. mem_floor ~16.3us; VALU ~7us.
//
// R11 theory: the additive wall (dur = mem + VALU, all of R1-R10) is a
// MEMORY-QUEUE convoy: one-shot kernels enqueue the whole per-CU footprint at
// t=0; FIFO interleaving means every wave's last line returns near stream-end
// -> chip-wide compute runs as a serial tail. Fix = steady-state re-issue:
// waves LOOP over tiles, consuming tile t while t+1 queues. (R6 tried this
// with 2 waves/SIMD + 96-VGPR buffers -> under Little's-law; this version is
// occupancy-correct.)
//
// Structure: 16 lanes/ray, lane=(q,sub): owns matrix row sub, gaussian g=sub,
// bones b=4k+q (6 iters). Tile = 4 rays/wave = 6KB, register double-buffer,
// 4 tiles/wave, 1024 blocks, launch_bounds(256,4) -> 16 waves/CU, ~96KB/CU in
// flight in steady state. Loads per (ray,k): 16 lanes read 256B CONTIGUOUS.
// sched_barrier(0) after each load block pins issue order (loads before the
// following compute). Math = R9/R10 straight-line (1-rcp merge, no branches).

#define NB 24
#define NG 4
#define BASE_SCALE 0.001f

template <int CTRL>
__device__ __forceinline__ float dpp_f(float x) {
    int r = __builtin_amdgcn_update_dpp(0, __float_as_int(x), CTRL, 0xF, 0xF, true);
    return __int_as_float(r);
}

__device__ __forceinline__ float frcp(float x) { return __builtin_amdgcn_rcpf(x); }

struct RayC { float ox, oy, oz, dx, dy, dz; };

__global__ __launch_bounds__(256, 4) void gauss_vis_kernel(
    const float* __restrict__ w2ls,
    const float* __restrict__ rays_o,
    const float* __restrict__ rays_d,
    const float* __restrict__ Gs,
    float* __restrict__ out,
    int R)
{
    __shared__ float4 P[NB * NG * 3];  // per (b,g): {s00,s01,s02,s11},{s12,s22,mu0,mu1},{mu2,c,-,-}

    const int tid = threadIdx.x;

    // ---- per-block param precompute (ray-independent) ----
    if (tid < NB * NG) {
        const float* gp = Gs + tid * 13;
        float mu0 = gp[0], mu1 = gp[1], mu2 = gp[2];
        float s0 = fabsf(gp[3]) + BASE_SCALE;
        float s1 = fabsf(gp[4]) + BASE_SCALE;
        float s2 = fabsf(gp[5]) + BASE_SCALE;
        float ax = gp[6], ay = gp[7], az = gp[8];
        float bx = gp[9], by = gp[10], bz = gp[11];
        float c = fabsf(gp[12]);
        float inv1 = 1.0f / sqrtf(ax * ax + ay * ay + az * az);
        float b1x = ax * inv1, b1y = ay * inv1, b1z = az * inv1;
        float dot = b1x * bx + b1y * by + b1z * bz;
        float t2x = bx - dot * b1x, t2y = by - dot * b1y, t2z = bz - dot * b1z;
        float inv2 = 1.0f / sqrtf(t2x * t2x + t2y * t2y + t2z * t2z);
        float b2x = t2x * inv2, b2y = t2y * inv2, b2z = t2z * inv2;
        float b3x = b1y * b2z - b1z * b2y;
        float b3y = b1z * b2x - b1x * b2z;
        float b3z = b1x * b2y - b1y * b2x;
        float w0 = 1.0f / (s0 * s0), w1 = 1.0f / (s1 * s1), w2 = 1.0f / (s2 * s2);
        float s00 = b1x * b1x * w0 + b1y * b1y * w1 + b1z * b1z * w2;
        float s01 = b1x * b2x * w0 + b1y * b2y * w1 + b1z * b2z * w2;
        float s02 = b1x * b3x * w0 + b1y * b3y * w1 + b1z * b3z * w2;
        float s11 = b2x * b2x * w0 + b2y * b2y * w1 + b2z * b2z * w2;
        float s12 = b2x * b3x * w0 + b2y * b3y * w1 + b2z * b3z * w2;
        float s22 = b3x * b3x * w0 + b3y * b3y * w1 + b3z * b3z * w2;
        P[tid * 3 + 0] = make_float4(s00, s01, s02, s11);
        P[tid * 3 + 1] = make_float4(s12, s22, mu0, mu1);
        P[tid * 3 + 2] = make_float4(mu2, c, 0.f, 0.f);
    }
    __syncthreads();

    const int lane16 = tid & 15;        // q*4+sub
    const int rsl = (tid & 63) >> 4;    // ray slot within wave (0..3)
    const int wid = blockIdx.x * 4 + (tid >> 6);  // global wave id
    const int Wstride = gridDim.x * 16; // rays advanced per tile step

    const float4* __restrict__ Wv = (const float4*)w2ls;
    const int pibase = lane16 * 3;      // P idx for (bone q, gauss sub) at k=0; +48/k

    // issue tile loads: 6 x float4 (256B contiguous per ray) + ray consts
    auto loadT = [&](float4 (&M)[6], RayC& rc, int rayt) {
        int r = rayt < R ? rayt : (R - 1);
        const float4* __restrict__ p = Wv + (size_t)r * 96 + lane16;
#pragma unroll
        for (int k = 0; k < 6; ++k) M[k] = p[k * 16];
        rc.ox = rays_o[r * 3 + 0]; rc.oy = rays_o[r * 3 + 1]; rc.oz = rays_o[r * 3 + 2];
        rc.dx = rays_d[r * 3 + 0]; rc.dy = rays_d[r * 3 + 1]; rc.dz = rays_d[r * 3 + 2];
    };

    // compute one tile (6 bones for this lane) + reduce over 16 lanes + store
    auto compT = [&](const float4 (&M)[6], const RayC& rc, int rayt) {
        float sum = 0.f;
#pragma unroll
        for (int k = 0; k < 6; ++k) {
            const float4 Mk = M[k];
            float o_s = fmaf(Mk.x, rc.ox, fmaf(Mk.y, rc.oy, fmaf(Mk.z, rc.oz, Mk.w)));
            float n_s = fmaf(Mk.x, rc.dx, fmaf(Mk.y, rc.dy, Mk.z * rc.dz));
            float o0 = dpp_f<0x00>(o_s), o1 = dpp_f<0x55>(o_s), o2 = dpp_f<0xAA>(o_s);
            float n0 = dpp_f<0x00>(n_s), n1 = dpp_f<0x55>(n_s), n2 = dpp_f<0xAA>(n_s);

            int pi = pibase + k * 48;
            float4 p0 = P[pi + 0];
            float4 p1 = P[pi + 1];
            float4 p2 = P[pi + 2];
            float s00 = p0.x, s01 = p0.y, s02 = p0.z, s11 = p0.w;
            float s12 = p1.x, s22 = p1.y;
            float d0 = p1.z - o0, d1 = p1.w - o1, d2 = p2.x - o2;  // mu - o
            float c = p2.y;

            float v0 = s00 * n0 + s01 * n1 + s02 * n2;
            float v1 = s01 * n0 + s11 * n1 + s12 * n2;
            float v2 = s02 * n0 + s12 * n1 + s22 * n2;
            float nSn = v0 * n0 + v1 * n1 + v2 * n2;   // n^T S n
            float nSd = v0 * d0 + v1 * d1 + v2 * d2;   // n^T S (mu-o)
            float q0 = s00 * d0 + s01 * d1 + s02 * d2;
            float q1 = s01 * d0 + s11 * d1 + s12 * d2;
            float q2 = s02 * d0 + s12 * d1 + s22 * d2;
            float quad = q0 * d0 + q1 * d1 + q2 * d2;  // d^T S d

            float r = __builtin_amdgcn_rsqf(nSn);      // 1/sqrt(nSn)
            float t = nSd * r;
            float resid = fmaf(t, t, -quad);           // exponent = 0.5*resid
            float mean = t * r;                        // mu_bar

            float ew = __expf(1.f - 100.f * mean);     // sigmoid denom part
            float z = (10.f - mean) * (nSn * r);       // (10-mean)*sqrt(nSn)
            float zz = z * z;
            float a = z * fmaf(0.070565992f, zz, 1.5976f);
            float ec = __expf(-a);                     // cubic-logistic Phi part
            float denom = (1.f + ew) * (1.f + ec);
            float ed = __expf(0.5f * resid);
            sum = fmaf(c * ed, frcp(denom), sum);
        }
        // reduce over the 16 lanes of this ray: quad DPP + xor4 + xor8
        sum += dpp_f<0xB1>(sum);        // quad_perm(1,0,3,2)
        sum += dpp_f<0x4E>(sum);        // quad_perm(2,3,0,1)
        sum += __shfl_xor(sum, 4, 64);
        sum += __shfl_xor(sum, 8, 64);
        if (lane16 == 0 && rayt < R) out[rayt] = __expf(-sum);
    };

    const int r0 = wid * 4 + rsl;
    const int r1 = r0 + Wstride;
    const int r2 = r1 + Wstride;
    const int r3 = r2 + Wstride;

    float4 A[6], B[6];
    RayC Ra, Rb;

    // software-pipelined 4-tile loop, fully unrolled (static buffers)
    loadT(A, Ra, r0);
    loadT(B, Rb, r1);
    __builtin_amdgcn_sched_barrier(0);
    compT(A, Ra, r0);
    loadT(A, Ra, r2);
    __builtin_amdgcn_sched_barrier(0);
    compT(B, Rb, r1);
    loadT(B, Rb, r3);
    __builtin_amdgcn_sched_barrier(0);
    compT(A, Ra, r2);
    compT(B, Rb, r3);
}

extern "C" void kernel_launch(void* const* d_in, const int* in_sizes, int n_in,
                              void* d_out, int out_size, void* d_ws, size_t ws_size,
                              hipStream_t stream) {
    const float* w2ls   = (const float*)d_in[0];
    const float* rays_o = (const float*)d_in[1];
    const float* rays_d = (const float*)d_in[2];
    const float* Gs     = (const float*)d_in[3];
    float* out = (float*)d_out;

    const int R = in_sizes[1] / 3;
    const int threads = 256;
    // 4 tiles/wave: blocks * (256/16 rays) * 4 tiles >= R
    const int blocks = (R + 63) / 64;   // R=65536 -> 1024 blocks (4/CU resident)
    gauss_vis_kernel<<<blocks, threads, 0, stream>>>(w2ls, rays_o, rays_d, Gs, out, R);
}

// Round 12
// 22.445 us; speedup vs baseline: 1.1080x; 1.1080x over previous
//
#include <hip/hip_runtime.h>
#include <math.h>

// GaussianVisibility: R rays x B=24 bones x G=4 gaussians -> shadow map (R,)
// w2ls (R,24,4,4) fp32 = 100.7 MB stream. Twice-validated model (R8/R9 +
// R10/R11 nulls): dur = mem_floor(~16.3us, schedule-invariant) + VALU_serial.
// Eight overlap attempts failed; only VALU cuts convert to duration (R9: 1:1).
//
// R12 change vs R9 (24.07us): VALU diet #2, structure untouched.
//  - Cholesky: S = U^T U per (b,g) ONCE in the block precompute; per-iter
//    quadratic forms become triangular matvecs Un(6)+Ud(6)+3 dots(9) = 21 ops
//    vs dense-symmetric 30. Algebraically identical (guarded sqrts).
//  - log2-domain exps: fold log2(e) into constants -> exp2 directly
//    (kills the 3 v_mul the compiler inserts for __expf).
//  - z = r*fma(nSn,10,-nSd)  ==  (10-mean)*sqrt(nSn), one op cheaper.
// Est. ~16 fewer VALU/iter (-14% VALU ~ -1.0us).
//
// Layout (R4/R9, proven): 8 lanes/ray, oct=(half,sub); lane owns matrix row
// sub, gaussian g=sub, bones 2k+half. o/n rows shared via DPP quad_perm;
// halves merged with __shfl_xor(4). Per-(b,g) params in LDS, once per block.

#define NB 24
#define NG 4
#define BASE_SCALE 0.001f

template <int CTRL>
__device__ __forceinline__ float dpp_f(float x) {
    int r = __builtin_amdgcn_update_dpp(0, __float_as_int(x), CTRL, 0xF, 0xF, true);
    return __int_as_float(r);
}

__device__ __forceinline__ float frcp(float x) { return __builtin_amdgcn_rcpf(x); }
__device__ __forceinline__ float fexp2(float x) { return __builtin_amdgcn_exp2f(x); }

__global__ __launch_bounds__(256, 8) void gauss_vis_kernel(
    const float* __restrict__ w2ls,
    const float* __restrict__ rays_o,
    const float* __restrict__ rays_d,
    const float* __restrict__ Gs,
    float* __restrict__ out,
    int R)
{
    // per (b,g): p0={u00,u01,u02,u11}, p1={u12,u22,mu0,mu1}, p2={mu2,c,-,-}
    __shared__ float4 P[NB * NG * 3];

    const int tid = threadIdx.x;
    const int gid = blockIdx.x * 256 + tid;
    const int ray0 = gid >> 3;
    const int ray = ray0 < R ? ray0 : (R - 1);
    const int oct = tid & 7;   // lane within the ray-octet
    const int sub = oct & 3;   // matrix row + gaussian index
    const int half = oct >> 2; // bone parity

    // ---- per-block param precompute (ray-independent), incl. Cholesky ----
    if (tid < NB * NG) {
        const float* gp = Gs + tid * 13;
        float mu0 = gp[0], mu1 = gp[1], mu2 = gp[2];
        float s0 = fabsf(gp[3]) + BASE_SCALE;
        float s1 = fabsf(gp[4]) + BASE_SCALE;
        float s2 = fabsf(gp[5]) + BASE_SCALE;
        float ax = gp[6], ay = gp[7], az = gp[8];
        float bx = gp[9], by = gp[10], bz = gp[11];
        float c = fabsf(gp[12]);
        float inv1 = 1.0f / sqrtf(ax * ax + ay * ay + az * az);
        float b1x = ax * inv1, b1y = ay * inv1, b1z = az * inv1;
        float dot = b1x * bx + b1y * by + b1z * bz;
        float t2x = bx - dot * b1x, t2y = by - dot * b1y, t2z = bz - dot * b1z;
        float inv2 = 1.0f / sqrtf(t2x * t2x + t2y * t2y + t2z * t2z);
        float b2x = t2x * inv2, b2y = t2y * inv2, b2z = t2z * inv2;
        float b3x = b1y * b2z - b1z * b2y;
        float b3y = b1z * b2x - b1x * b2z;
        float b3z = b1x * b2y - b1y * b2x;
        float w0 = 1.0f / (s0 * s0), w1 = 1.0f / (s1 * s1), w2 = 1.0f / (s2 * s2);
        float s00 = b1x * b1x * w0 + b1y * b1y * w1 + b1z * b1z * w2;
        float s01 = b1x * b2x * w0 + b1y * b2y * w1 + b1z * b2z * w2;
        float s02 = b1x * b3x * w0 + b1y * b3y * w1 + b1z * b3z * w2;
        float s11 = b2x * b2x * w0 + b2y * b2y * w1 + b2z * b2z * w2;
        float s12 = b2x * b3x * w0 + b2y * b3y * w1 + b2z * b3z * w2;
        float s22 = b3x * b3x * w0 + b3y * b3y * w1 + b3z * b3z * w2;
        // Cholesky S = U^T U (U upper). Guarded against fp cancellation.
        float u00 = sqrtf(fmaxf(s00, 1e-20f));
        float iu00 = 1.0f / u00;
        float u01 = s01 * iu00;
        float u02 = s02 * iu00;
        float u11 = sqrtf(fmaxf(s11 - u01 * u01, 1e-20f));
        float u12 = (s12 - u01 * u02) / u11;
        float u22 = sqrtf(fmaxf(s22 - u02 * u02 - u12 * u12, 1e-20f));
        P[tid * 3 + 0] = make_float4(u00, u01, u02, u11);
        P[tid * 3 + 1] = make_float4(u12, u22, mu0, mu1);
        P[tid * 3 + 2] = make_float4(mu2, c, 0.f, 0.f);
    }
    __syncthreads();

    const float rox = rays_o[ray * 3 + 0];
    const float roy = rays_o[ray * 3 + 1];
    const float roz = rays_o[ray * 3 + 2];
    const float rdx = rays_d[ray * 3 + 0];
    const float rdy = rays_d[ray * 3 + 1];
    const float rdz = rays_d[ray * 3 + 2];

    // bone b = 2k + half lives at Wp[k*8] (float4 units)
    const float4* __restrict__ Wp =
        (const float4*)w2ls + ((size_t)ray * (NB * 4) + half * 4 + sub);
    const int pi0 = (half * NG + sub) * 3;  // P index for bone `half`, +24 per k

    float sum = 0.f;
#pragma unroll 2
    for (int k = 0; k < 12; ++k) {
        const float4 M = Wp[k * 8];
        float o_s = fmaf(M.x, rox, fmaf(M.y, roy, fmaf(M.z, roz, M.w)));  // homog 1
        float n_s = fmaf(M.x, rdx, fmaf(M.y, rdy, M.z * rdz));            // homog 0
        float o0 = dpp_f<0x00>(o_s), o1 = dpp_f<0x55>(o_s), o2 = dpp_f<0xAA>(o_s);
        float n0 = dpp_f<0x00>(n_s), n1 = dpp_f<0x55>(n_s), n2 = dpp_f<0xAA>(n_s);

        int pi = pi0 + k * 24;
        float4 p0 = P[pi + 0];
        float4 p1 = P[pi + 1];
        float4 p2 = P[pi + 2];
        float u00 = p0.x, u01 = p0.y, u02 = p0.z, u11 = p0.w;
        float u12 = p1.x, u22 = p1.y;
        float d0 = p1.z - o0, d1 = p1.w - o1, d2 = p2.x - o2;  // mu - o
        float c = p2.y;

        // triangular matvecs: Un, Ud  (S = U^T U)
        float un0 = fmaf(u02, n2, fmaf(u01, n1, u00 * n0));
        float un1 = fmaf(u12, n2, u11 * n1);
        float un2 = u22 * n2;
        float ud0 = fmaf(u02, d2, fmaf(u01, d1, u00 * d0));
        float ud1 = fmaf(u12, d2, u11 * d1);
        float ud2 = u22 * d2;

        float nSn = fmaf(un2, un2, fmaf(un1, un1, un0 * un0));  // n^T S n
        float nSd = fmaf(un2, ud2, fmaf(un1, ud1, un0 * ud0));  // n^T S (mu-o)
        float quad = fmaf(ud2, ud2, fmaf(ud1, ud1, ud0 * ud0)); // d^T S d

        float r = __builtin_amdgcn_rsqf(nSn);      // 1/sqrt(nSn)
        float t = nSd * r;
        float resid = fmaf(t, t, -quad);           // exponent*2 (<=0)

        // ed = exp(0.5*resid); ew = exp(1-100*mean); ec = exp(-z*(1.5976+...z^2))
        // all in exp2 domain (constants pre-multiplied by log2 e)
        float ed = fexp2(0.72134752f * resid);
        float ew = fexp2(fmaf(t * r, -144.26950f, 1.4426950f));
        float z = r * fmaf(nSn, 10.f, -nSd);       // (10-mean)*sqrt(nSn)
        float zz = z * z;
        float ec = fexp2(-z * fmaf(0.10180843f, zz, 2.3048389f));

        float denom = (1.f + ew) * (1.f + ec);
        sum = fmaf(c * ed, frcp(denom), sum);
    }

    // reduce: quad butterfly (DPP), then merge the two quads of the octet
    sum += dpp_f<0xB1>(sum);       // quad_perm(1,0,3,2)
    sum += dpp_f<0x4E>(sum);       // quad_perm(2,3,0,1)
    sum += __shfl_xor(sum, 4, 64); // half <-> half
    if (oct == 0 && ray0 < R) out[ray0] = __expf(-sum);
}

extern "C" void kernel_launch(void* const* d_in, const int* in_sizes, int n_in,
                              void* d_out, int out_size, void* d_ws, size_t ws_size,
                              hipStream_t stream) {
    const float* w2ls   = (const float*)d_in[0];
    const float* rays_o = (const float*)d_in[1];
    const float* rays_d = (const float*)d_in[2];
    const float* Gs     = (const float*)d_in[3];
    float* out = (float*)d_out;

    const int R = in_sizes[1] / 3;
    const int threads = 256;
    const long long total = (long long)R * 8;
    const int blocks = (int)((total + threads - 1) / threads);
    gauss_vis_kernel<<<blocks, threads, 0, stream>>>(w2ls, rays_o, rays_d, Gs, out, R);
}

// Round 14
// 22.284 us; speedup vs baseline: 1.1161x; 1.0072x over previous
//
#include <hip/hip_runtime.h>
#include <math.h>

// GaussianVisibility: R rays x B=24 bones x G=4 gaussians -> shadow map (R,)
// w2ls (R,24,4,4) fp32 = 100.7 MB stream. Validated model (R8-R12):
// dur = mem_floor(~16.3us, schedule-invariant) + VALU_serial (~6.1us).
// VALU cuts convert ~1:1 to duration (R9, R12). Overlap attempts: 10x null.
//
// R14 = R13 with the macro/brace compile fix (C_TEN constant).
// Packed-FP32 (VOP3P) pair processing: each lane processes its 12 bones as
// 6 PAIRS (bA=2j+half, bB=2j+12+half); all elementwise math between the DPP
// broadcasts and the transcendentals is float2 (ext_vector) ->
// v_pk_fma_f32/v_pk_mul_f32/v_pk_add_f32 (2 FP32/lane/instr; 157 TF spec is
// the UNPACKED rate). Trans (rsq/exp2/rcp) stay scalar per half. Params
// stored A/B-INTERLEAVED in LDS so each ds_read_b128 delivers two f2
// operands in consecutive VGPRs; c folded to lc=log2(c) in the ed exponent.
// Est. per-bone issue 122 -> ~85 cyc => VALU ~6.1 -> ~4.3us.
//
// Layout (R4/R9, proven): 8 lanes/ray, oct=(half,sub); lane owns matrix row
// sub, gaussian g=sub, bones of parity half. o/n rows shared via DPP
// quad_perm; halves merged with __shfl_xor(4).

#define NB 24
#define NG 4
#define BASE_SCALE 0.001f

typedef float f2 __attribute__((ext_vector_type(2)));
#define PKF(a, b, c) __builtin_elementwise_fma((f2)(a), (f2)(b), (f2)(c))

template <int CTRL>
__device__ __forceinline__ float dpp_f(float x) {
    int r = __builtin_amdgcn_update_dpp(0, __float_as_int(x), CTRL, 0xF, 0xF, true);
    return __int_as_float(r);
}

__device__ __forceinline__ float frcp(float x) { return __builtin_amdgcn_rcpf(x); }
__device__ __forceinline__ float fexp2(float x) { return __builtin_amdgcn_exp2f(x); }

__global__ __launch_bounds__(256, 8) void gauss_vis_kernel(
    const float* __restrict__ w2ls,
    const float* __restrict__ rays_o,
    const float* __restrict__ rays_d,
    const float* __restrict__ Gs,
    float* __restrict__ out,
    int R)
{
    // Ppk[j][half][sub]: 5 float4 = 20 floats, A/B interleaved:
    // {u00A,u00B,u01A,u01B},{u02A,u02B,u11A,u11B},{u12A,u12B,u22A,u22B},
    // {mu0A,mu0B,mu1A,mu1B},{mu2A,mu2B,lcA,lcB}
    __shared__ float4 Ppk4[6 * 2 * 4 * 5];

    const int tid = threadIdx.x;
    const int gid = blockIdx.x * 256 + tid;
    const int ray0 = gid >> 3;
    const int ray = ray0 < R ? ray0 : (R - 1);
    const int oct = tid & 7;   // lane within the ray-octet
    const int sub = oct & 3;   // matrix row + gaussian index
    const int half = oct >> 2; // bone parity

    // ---- per-block param precompute (ray-independent): Cholesky + interleave ----
    if (tid < NB * NG) {
        const int b = tid >> 2, g = tid & 3;
        const float* gp = Gs + tid * 13;
        float mu0 = gp[0], mu1 = gp[1], mu2 = gp[2];
        float s0 = fabsf(gp[3]) + BASE_SCALE;
        float s1 = fabsf(gp[4]) + BASE_SCALE;
        float s2 = fabsf(gp[5]) + BASE_SCALE;
        float ax = gp[6], ay = gp[7], az = gp[8];
        float bx = gp[9], by = gp[10], bz = gp[11];
        float c = fabsf(gp[12]);
        float inv1 = 1.0f / sqrtf(ax * ax + ay * ay + az * az);
        float b1x = ax * inv1, b1y = ay * inv1, b1z = az * inv1;
        float dot = b1x * bx + b1y * by + b1z * bz;
        float t2x = bx - dot * b1x, t2y = by - dot * b1y, t2z = bz - dot * b1z;
        float inv2 = 1.0f / sqrtf(t2x * t2x + t2y * t2y + t2z * t2z);
        float b2x = t2x * inv2, b2y = t2y * inv2, b2z = t2z * inv2;
        float b3x = b1y * b2z - b1z * b2y;
        float b3y = b1z * b2x - b1x * b2z;
        float b3z = b1x * b2y - b1y * b2x;
        float w0 = 1.0f / (s0 * s0), w1 = 1.0f / (s1 * s1), w2 = 1.0f / (s2 * s2);
        float s00 = b1x * b1x * w0 + b1y * b1y * w1 + b1z * b1z * w2;
        float s01 = b1x * b2x * w0 + b1y * b2y * w1 + b1z * b2z * w2;
        float s02 = b1x * b3x * w0 + b1y * b3y * w1 + b1z * b3z * w2;
        float s11 = b2x * b2x * w0 + b2y * b2y * w1 + b2z * b2z * w2;
        float s12 = b2x * b3x * w0 + b2y * b3y * w1 + b2z * b3z * w2;
        float s22 = b3x * b3x * w0 + b3y * b3y * w1 + b3z * b3z * w2;
        // Cholesky S = U^T U (guarded)
        float u00 = sqrtf(fmaxf(s00, 1e-20f));
        float iu00 = 1.0f / u00;
        float u01 = s01 * iu00;
        float u02 = s02 * iu00;
        float u11 = sqrtf(fmaxf(s11 - u01 * u01, 1e-20f));
        float u12 = (s12 - u01 * u02) / u11;
        float u22 = sqrtf(fmaxf(s22 - u02 * u02 - u12 * u12, 1e-20f));
        float lc = log2f(c);
        // interleaved write: sel = (b>=12), j = (b-12*sel)>>1, hlf = b&1
        const int sel = b >= 12 ? 1 : 0;
        const int bb = b - 12 * sel;
        const int j = bb >> 1, hlf = b & 1;
        float* dst = (float*)&Ppk4[((j * 2 + hlf) * 4 + g) * 5];
        dst[0 * 2 + sel] = u00;  dst[1 * 2 + sel] = u01;
        dst[2 * 2 + sel] = u02;  dst[3 * 2 + sel] = u11;
        dst[4 * 2 + sel] = u12;  dst[5 * 2 + sel] = u22;
        dst[6 * 2 + sel] = mu0;  dst[7 * 2 + sel] = mu1;
        dst[8 * 2 + sel] = mu2;  dst[9 * 2 + sel] = lc;
    }
    __syncthreads();

    const float rox = rays_o[ray * 3 + 0];
    const float roy = rays_o[ray * 3 + 1];
    const float roz = rays_o[ray * 3 + 2];
    const float rdx = rays_d[ray * 3 + 0];
    const float rdy = rays_d[ray * 3 + 1];
    const float rdz = rays_d[ray * 3 + 2];

    const float4* __restrict__ Wp =
        (const float4*)w2ls + ((size_t)ray * 96 + half * 4 + sub);
    const float4* __restrict__ Pb = Ppk4 + (half * 4 + sub) * 5;

    const f2 C_ED  = {0.72134752f, 0.72134752f};   // log2e/2
    const f2 C_EWm = {-144.26950f, -144.26950f};   // -100*log2e
    const f2 C_EWb = {1.4426950f, 1.4426950f};     // log2e
    const f2 C_ECa = {0.10180843f, 0.10180843f};   // 0.070566*log2e
    const f2 C_ECb = {2.3048389f, 2.3048389f};     // 1.5976*log2e
    const f2 C_ONE = {1.f, 1.f};
    const f2 C_TEN = {10.f, 10.f};

    f2 sum2 = {0.f, 0.f};
#pragma unroll 1
    for (int j = 0; j < 6; ++j) {
        const float4 MA = Wp[j * 8];        // bone 2j+half
        const float4 MB = Wp[j * 8 + 48];   // bone 2j+12+half
        float o_sA = fmaf(MA.x, rox, fmaf(MA.y, roy, fmaf(MA.z, roz, MA.w)));
        float o_sB = fmaf(MB.x, rox, fmaf(MB.y, roy, fmaf(MB.z, roz, MB.w)));
        float n_sA = fmaf(MA.x, rdx, fmaf(MA.y, rdy, MA.z * rdz));
        float n_sB = fmaf(MB.x, rdx, fmaf(MB.y, rdy, MB.z * rdz));
        f2 o0, o1, o2, n0, n1, n2;
        o0.x = dpp_f<0x00>(o_sA); o0.y = dpp_f<0x00>(o_sB);
        o1.x = dpp_f<0x55>(o_sA); o1.y = dpp_f<0x55>(o_sB);
        o2.x = dpp_f<0xAA>(o_sA); o2.y = dpp_f<0xAA>(o_sB);
        n0.x = dpp_f<0x00>(n_sA); n0.y = dpp_f<0x00>(n_sB);
        n1.x = dpp_f<0x55>(n_sA); n1.y = dpp_f<0x55>(n_sB);
        n2.x = dpp_f<0xAA>(n_sA); n2.y = dpp_f<0xAA>(n_sB);

        const float4* pp = Pb + j * 40;
        float4 q0 = pp[0], q1 = pp[1], q2 = pp[2], q3 = pp[3], q4 = pp[4];
        f2 u00 = ((const f2*)&q0)[0], u01 = ((const f2*)&q0)[1];
        f2 u02 = ((const f2*)&q1)[0], u11 = ((const f2*)&q1)[1];
        f2 u12 = ((const f2*)&q2)[0], u22 = ((const f2*)&q2)[1];
        f2 mu0 = ((const f2*)&q3)[0], mu1 = ((const f2*)&q3)[1];
        f2 mu2 = ((const f2*)&q4)[0], lc  = ((const f2*)&q4)[1];

        f2 d0 = mu0 - o0, d1 = mu1 - o1, d2 = mu2 - o2;   // mu - o
        f2 un0 = PKF(u02, n2, PKF(u01, n1, u00 * n0));    // U n
        f2 un1 = PKF(u12, n2, u11 * n1);
        f2 un2 = u22 * n2;
        f2 ud0 = PKF(u02, d2, PKF(u01, d1, u00 * d0));    // U d
        f2 ud1 = PKF(u12, d2, u11 * d1);
        f2 ud2 = u22 * d2;
        f2 nSn = PKF(un2, un2, PKF(un1, un1, un0 * un0)); // n^T S n
        f2 nSd = PKF(un2, ud2, PKF(un1, ud1, un0 * ud0)); // n^T S d
        f2 quad = PKF(ud2, ud2, PKF(ud1, ud1, ud0 * ud0));// d^T S d

        f2 r; r.x = __builtin_amdgcn_rsqf(nSn.x); r.y = __builtin_amdgcn_rsqf(nSn.y);
        f2 t = nSd * r;
        f2 resid = PKF(t, t, -quad);                      // 2*exponent (<=0)
        f2 mean = t * r;
        f2 edarg = PKF(C_ED, resid, lc);                  // log2(c*exp(resid/2))
        f2 ewarg = PKF(mean, C_EWm, C_EWb);               // log2(exp(1-100*mean))
        f2 zi = PKF(nSn, C_TEN, -nSd);
        f2 z = zi * r;                                    // (10-mean)*sqrt(nSn)
        f2 zz = z * z;
        f2 ecarg = -z * PKF(C_ECa, zz, C_ECb);            // cubic-logistic Phi
        f2 ed, ew, ec;
        ed.x = fexp2(edarg.x); ed.y = fexp2(edarg.y);
        ew.x = fexp2(ewarg.x); ew.y = fexp2(ewarg.y);
        ec.x = fexp2(ecarg.x); ec.y = fexp2(ecarg.y);
        f2 den = (C_ONE + ew) * (C_ONE + ec);
        f2 rd; rd.x = frcp(den.x); rd.y = frcp(den.y);
        sum2 = PKF(ed, rd, sum2);
    }
    float sum = sum2.x + sum2.y;

    // reduce: quad butterfly (DPP), then merge the two quads of the octet
    sum += dpp_f<0xB1>(sum);       // quad_perm(1,0,3,2)
    sum += dpp_f<0x4E>(sum);       // quad_perm(2,3,0,1)
    sum += __shfl_xor(sum, 4, 64); // half <-> half
    if (oct == 0 && ray0 < R) out[ray0] = __expf(-sum);
}

extern "C" void kernel_launch(void* const* d_in, const int* in_sizes, int n_in,
                              void* d_out, int out_size, void* d_ws, size_t ws_size,
                              hipStream_t stream) {
    const float* w2ls   = (const float*)d_in[0];
    const float* rays_o = (const float*)d_in[1];
    const float* rays_d = (const float*)d_in[2];
    const float* Gs     = (const float*)d_in[3];
    float* out = (float*)d_out;

    const int R = in_sizes[1] / 3;
    const int threads = 256;
    const long long total = (long long)R * 8;
    const int blocks = (int)((total + threads - 1) / threads);
    gauss_vis_kernel<<<blocks, threads, 0, stream>>>(w2ls, rays_o, rays_d, Gs, out, R);
}